// Round 3
// baseline (1777.941 us; speedup 1.0000x reference)
//
#include <hip/hip_runtime.h>

#define S 32
#define KN 26
#define NLOC 3
#define NFUNC 14
#define NDIST 9
#define DTC 0.3f

__device__ __forceinline__ float frcp(float x) { return __builtin_amdgcn_rcpf(x); }

// tanh(x) = 1 - 2/(e^{2x}+1); exact saturation at +/-inf via exp->inf/0.
__device__ __forceinline__ float ftanh(float x) {
    float e = __expf(2.0f * x);
    return 1.0f - 2.0f * frcp(e + 1.0f);
}

// jax.nn.gelu(approximate=True)
__device__ __forceinline__ float fgelu(float x) {
    float t = ftanh(0.7978845608028654f * x * (1.0f + 0.044715f * x * x));
    return 0.5f * x * (1.0f + t);
}

// acc[j] += in[i] * W[(rowoff+i)*S + j]; W lane-uniform -> s_load, SGPR FMA operand
#define MAT32(acc, inv, Wp, rowoff)                                  \
    _Pragma("unroll")                                                \
    for (int i_ = 0; i_ < S; i_++) {                                 \
        float a_ = (inv)[i_];                                        \
        _Pragma("unroll")                                            \
        for (int j_ = 0; j_ < S; j_++)                               \
            (acc)[j_] += a_ * (Wp)[((rowoff) + i_) * S + j_];        \
    }

#define LOAD_F4(buf, ptr)                                            \
    {                                                                \
        const float4* rp_ = reinterpret_cast<const float4*>(ptr);    \
        _Pragma("unroll")                                            \
        for (int i_ = 0; i_ < S / 4; i_++) (buf)[i_] = rp_[i_];      \
    }

#define UNPACK(dst, buf)                                             \
    {                                                                \
        _Pragma("unroll")                                            \
        for (int i_ = 0; i_ < S / 4; i_++) {                         \
            (dst)[4*i_+0] = (buf)[i_].x; (dst)[4*i_+1] = (buf)[i_].y;\
            (dst)[4*i_+2] = (buf)[i_].z; (dst)[4*i_+3] = (buf)[i_].w;\
        }                                                            \
    }

__global__ __launch_bounds__(64, 1) void moe_kernel(
    const float* __restrict__ cs,  const float* __restrict__ nb,
    const float* __restrict__ Wl,  const float* __restrict__ bl,
    const float* __restrict__ Wm,  const float* __restrict__ bm,
    const float* __restrict__ Wu,  const float* __restrict__ bu,
    const float* __restrict__ Wc,  const float* __restrict__ bc,
    const float* __restrict__ Wd,  const float* __restrict__ bd,
    const float* __restrict__ lng, const float* __restrict__ lnb,
    const float* __restrict__ gW1, const float* __restrict__ gb1,
    const float* __restrict__ gW2, const float* __restrict__ gb2,
    float* __restrict__ out, int B)
{
    const int b = blockIdx.x * blockDim.x + threadIdx.x;
    if (b >= B) return;

    const float* nbp = nb + (size_t)b * (KN * S);

    float act[S];
    #pragma unroll
    for (int s = 0; s < S; s++) act[s] = 0.0f;

    // ---- Phase 1: local rows 0..2 -> loc.  live: act, loc, 3x buf (transient)
    float loc[S];
    {
        float4 q0[S/4], q1[S/4], q2[S/4];
        LOAD_F4(q0, nbp + 0 * S);
        LOAD_F4(q1, nbp + 1 * S);
        LOAD_F4(q2, nbp + 2 * S);
        float r0[S], r1[S], r2[S];
        UNPACK(r0, q0); UNPACK(r1, q1); UNPACK(r2, q2);
        #pragma unroll
        for (int s = 0; s < S; s++) {
            loc[s] = (r0[s] + r1[s] + r2[s]) * (1.0f / NLOC);
            act[s] += fabsf(r0[s]) + fabsf(r1[s]) + fabsf(r2[s]);
        }
    }

    // ---- Phase 2: func rows 3..16 streamed in pairs (ping-pong, no copies).
    // x NOT loaded yet: live = act, loc, agg, tmp, r, bufs  (~224 max)
    float agg[S];
    #pragma unroll
    for (int j = 0; j < S; j++) agg[j] = 0.0f;
    {
        float4 bufA[S/4], bufB[S/4];
        LOAD_F4(bufA, nbp + 3 * S);          // prologue: row 3
        #pragma unroll 1
        for (int t = 0; t < 7; t++) {
            const int r0 = 3 + 2 * t;
            LOAD_F4(bufB, nbp + (r0 + 1) * S);   // in flight during process(A)
            {
                float r[S];
                UNPACK(r, bufA);
                float tmp[S];
                #pragma unroll
                for (int j = 0; j < S; j++) tmp[j] = bm[j];
                MAT32(tmp, r, Wm, 0);
                #pragma unroll
                for (int j = 0; j < S; j++) agg[j] += fgelu(tmp[j]);
                #pragma unroll
                for (int s = 0; s < S; s++) act[s] += fabsf(r[s]);
            }
            LOAD_F4(bufA, nbp + (r0 + 2) * S);   // t=6 loads row 17 (valid mem, unused)
            {
                float r[S];
                UNPACK(r, bufB);
                float tmp[S];
                #pragma unroll
                for (int j = 0; j < S; j++) tmp[j] = bm[j];
                MAT32(tmp, r, Wm, 0);
                #pragma unroll
                for (int j = 0; j < S; j++) agg[j] += fgelu(tmp[j]);
                #pragma unroll
                for (int s = 0; s < S; s++) act[s] += fabsf(r[s]);
            }
        }
    }

    // ---- Phase 3: load x; yl = x + tanh([x, loc] @ Wl + bl)   (retires loc)
    float x[S];
    {
        float4 qx[S/4];
        LOAD_F4(qx, cs + (size_t)b * S);
        UNPACK(x, qx);
    }
    float yl[S];
    {
        float acc[S];
        #pragma unroll
        for (int j = 0; j < S; j++) acc[j] = bl[j];
        MAT32(acc, x, Wl, 0);
        MAT32(acc, loc, Wl, S);
        #pragma unroll
        for (int j = 0; j < S; j++) yl[j] = x[j] + ftanh(acc[j]);
    }

    // ---- Phase 4: yf   (retires agg)
    float yf[S];
    {
        #pragma unroll
        for (int i = 0; i < S; i++) agg[i] *= (1.0f / NFUNC);
        float acc[S];
        #pragma unroll
        for (int j = 0; j < S; j++) acc[j] = bu[j];
        MAT32(acc, x, Wu, 0);
        MAT32(acc, agg, Wu, S);
        float h[S];
        #pragma unroll
        for (int j = 0; j < S; j++) h[j] = x[j] + ftanh(acc[j]);
        float a2[S];
        #pragma unroll
        for (int j = 0; j < S; j++) a2[j] = bc[j];
        MAT32(a2, h, Wc, 0);
        #pragma unroll
        for (int j = 0; j < S; j++) yf[j] = h[j] + DTC * ftanh(a2[j]);
    }

    // ---- Phase 5: dist rows 17..25 in pairs (64-float transient)
    float dist[S];
    #pragma unroll
    for (int s = 0; s < S; s++) dist[s] = 0.0f;
    #pragma unroll 1
    for (int t = 0; t < 4; t++) {
        float4 qa[S/4], qb[S/4];
        LOAD_F4(qa, nbp + (NLOC + NFUNC + 2 * t + 0) * S);
        LOAD_F4(qb, nbp + (NLOC + NFUNC + 2 * t + 1) * S);
        float ra[S], rb[S];
        UNPACK(ra, qa); UNPACK(rb, qb);
        #pragma unroll
        for (int s = 0; s < S; s++) {
            dist[s] += ra[s] + rb[s];
            act[s]  += fabsf(ra[s]) + fabsf(rb[s]);
        }
    }
    {   // row 25
        float4 qa[S/4];
        LOAD_F4(qa, nbp + (NLOC + NFUNC + 8) * S);
        float ra[S];
        UNPACK(ra, qa);
        #pragma unroll
        for (int s = 0; s < S; s++) { dist[s] += ra[s]; act[s] += fabsf(ra[s]); }
    }
    #pragma unroll
    for (int s = 0; s < S; s++) dist[s] *= (1.0f / NDIST);

    // ---- Phase 6: gate  (retires act)
    float gate0, gate1, gate2;
    {
        float mu = 0.0f;
        #pragma unroll
        for (int s = 0; s < S; s++) mu += x[s];
        mu *= (1.0f / S);
        float var = 0.0f;
        #pragma unroll
        for (int s = 0; s < S; s++) { float d = x[s] - mu; var += d * d; }
        var *= (1.0f / S);
        float rstd = rsqrtf(var + 1e-5f);

        float g1[8];
        #pragma unroll
        for (int t = 0; t < 8; t++) g1[t] = gb1[t];
        #pragma unroll
        for (int i = 0; i < S; i++) {
            float a = (x[i] - mu) * rstd * lng[i] + lnb[i];
            #pragma unroll
            for (int t = 0; t < 8; t++) g1[t] += a * gW1[i * 8 + t];
        }
        #pragma unroll
        for (int i = 0; i < S; i++) {
            float a = act[i] * (1.0f / KN);
            #pragma unroll
            for (int t = 0; t < 8; t++) g1[t] += a * gW1[(S + i) * 8 + t];
        }
        float lg0 = gb2[0], lg1 = gb2[1], lg2 = gb2[2];
        #pragma unroll
        for (int t = 0; t < 8; t++) {
            float g = fgelu(g1[t]);
            lg0 += g * gW2[t * 3 + 0];
            lg1 += g * gW2[t * 3 + 1];
            lg2 += g * gW2[t * 3 + 2];
        }
        float mx = fmaxf(lg0, fmaxf(lg1, lg2));
        float e0 = __expf(lg0 - mx), e1 = __expf(lg1 - mx), e2 = __expf(lg2 - mx);
        float rs = frcp(e0 + e1 + e2);
        gate0 = e0 * rs; gate1 = e1 * rs; gate2 = e2 * rs;
    }

    // ---- Phase 7: comb (retires yl,yf); CNF (x -> xt)
    float comb[S];
    #pragma unroll
    for (int s = 0; s < S; s++) comb[s] = gate0 * yl[s] + gate1 * yf[s];

    #pragma unroll 1
    for (int it = 0; it < 3; it++) {
        float acc[S];
        #pragma unroll
        for (int j = 0; j < S; j++) acc[j] = bd[j];
        MAT32(acc, x, Wd, 0);
        MAT32(acc, dist, Wd, S);
        #pragma unroll
        for (int j = 0; j < S; j++) x[j] += DTC * ftanh(acc[j]);
    }
    #pragma unroll
    for (int s = 0; s < S; s++) comb[s] += gate2 * x[s];

    // ---- store: combined (B,32) then gate (B,3)
    {
        float4* op = reinterpret_cast<float4*>(out + (size_t)b * S);
        #pragma unroll
        for (int i = 0; i < S / 4; i++)
            op[i] = make_float4(comb[4*i+0], comb[4*i+1], comb[4*i+2], comb[4*i+3]);
        float* gp = out + (size_t)B * S + (size_t)b * 3;
        gp[0] = gate0; gp[1] = gate1; gp[2] = gate2;
    }
}

extern "C" void kernel_launch(void* const* d_in, const int* in_sizes, int n_in,
                              void* d_out, int out_size, void* d_ws, size_t ws_size,
                              hipStream_t stream)
{
    const int B = in_sizes[0] / S;
    dim3 block(64);
    dim3 grid((B + 63) / 64);
    hipLaunchKernelGGL(moe_kernel, grid, block, 0, stream,
        (const float*)d_in[0],  (const float*)d_in[1],
        (const float*)d_in[2],  (const float*)d_in[3],
        (const float*)d_in[4],  (const float*)d_in[5],
        (const float*)d_in[6],  (const float*)d_in[7],
        (const float*)d_in[8],  (const float*)d_in[9],
        (const float*)d_in[10], (const float*)d_in[11],
        (const float*)d_in[12], (const float*)d_in[13],
        (const float*)d_in[14], (const float*)d_in[15],
        (const float*)d_in[16], (const float*)d_in[17],
        (float*)d_out, B);
}

// Round 4
// 1521.849 us; speedup vs baseline: 1.1683x; 1.1683x over previous
//
#include <hip/hip_runtime.h>

#define S 32
#define DTC 0.3f

// LDS word offsets: per-thread columns, addr = slot + c*64 + t  (c=channel, t=lane)
// 2-way bank aliasing (lanes t and t+32) is free [m136].
#define SL_X    0       // x, parked whole kernel
#define SL_A    2048    // agg (func) -> dist (reused after Wu)
#define SL_ACT  4096    // sum |nb| accumulator (RMW)
#define SL_YL   6144    // y_local, parked until final combine
#define LDSW    8192    // 32 KB/block -> 4 blocks/CU co-resident

__device__ __forceinline__ float frcp(float x) { return __builtin_amdgcn_rcpf(x); }

// tanh(x) = 1 - 2/(e^{2x}+1); exact saturation via exp->inf/0.
__device__ __forceinline__ float ftanh(float x) {
    float e = __expf(2.0f * x);
    return 1.0f - 2.0f * frcp(e + 1.0f);
}

// jax.nn.gelu(approximate=True)
__device__ __forceinline__ float fgelu(float x) {
    float t = ftanh(0.7978845608028654f * x * (1.0f + 0.044715f * x * x));
    return 0.5f * x * (1.0f + t);
}

#define LOAD_ROW(dst, ptr)                                           \
    {                                                                \
        const float4* rp_ = reinterpret_cast<const float4*>(ptr);    \
        _Pragma("unroll")                                            \
        for (int i_ = 0; i_ < 8; i_++) {                             \
            float4 v_ = rp_[i_];                                     \
            (dst)[4*i_+0] = v_.x; (dst)[4*i_+1] = v_.y;              \
            (dst)[4*i_+2] = v_.z; (dst)[4*i_+3] = v_.w;              \
        }                                                            \
    }

// acc[j] += a[i] * W[(row0+i)*S+j]; W index wave-uniform -> s_load/SGPR operand
#define MAT_R(acc, av, Wp, row0)                                     \
    _Pragma("unroll")                                                \
    for (int i_ = 0; i_ < S; i_++) {                                 \
        float a_ = (av)[i_];                                         \
        _Pragma("unroll")                                            \
        for (int j_ = 0; j_ < S; j_++)                               \
            (acc)[j_] += a_ * (Wp)[((row0)+i_)*S + j_];              \
    }

// same, but a[i] streamed from this thread's LDS column with scale
#define MAT_L(acc, slot, scale, Wp, row0)                            \
    _Pragma("unroll")                                                \
    for (int i_ = 0; i_ < S; i_++) {                                 \
        float a_ = lds[(slot) + i_*64 + t] * (scale);                \
        _Pragma("unroll")                                            \
        for (int j_ = 0; j_ < S; j_++)                               \
            (acc)[j_] += a_ * (Wp)[((row0)+i_)*S + j_];              \
    }

__global__ __launch_bounds__(64, 1) void moe_kernel(
    const float* __restrict__ cs,  const float* __restrict__ nb,
    const float* __restrict__ Wl,  const float* __restrict__ bl,
    const float* __restrict__ Wm,  const float* __restrict__ bm,
    const float* __restrict__ Wu,  const float* __restrict__ bu,
    const float* __restrict__ Wc,  const float* __restrict__ bc,
    const float* __restrict__ Wd,  const float* __restrict__ bd,
    const float* __restrict__ lng, const float* __restrict__ lnb,
    const float* __restrict__ gW1, const float* __restrict__ gb1,
    const float* __restrict__ gW2, const float* __restrict__ gb2,
    float* __restrict__ out, int B)
{
    __shared__ float lds[LDSW];
    const int t = threadIdx.x;
    int b = blockIdx.x * 64 + t;
    if (b >= B) b = B - 1;   // B%64==0 in this harness; clamp is benign
    const float* nbp = nb + (size_t)b * (26 * S);

    // ---- startup: x + 3 local rows issued together (latencies overlap)
    float xr[S], r0[S], r1[S], r2[S];
    LOAD_ROW(xr, cs + (size_t)b * S);
    LOAD_ROW(r0, nbp + 0 * S);
    LOAD_ROW(r1, nbp + 1 * S);
    LOAD_ROW(r2, nbp + 2 * S);

    // park x
    #pragma unroll
    for (int c = 0; c < S; c++) lds[SL_X + c*64 + t] = xr[c];

    // loc (regs, short-lived) + act init (LDS)
    float loc[S];
    #pragma unroll
    for (int c = 0; c < S; c++) {
        loc[c] = (r0[c] + r1[c] + r2[c]) * (1.0f / 3.0f);
        lds[SL_ACT + c*64 + t] = fabsf(r0[c]) + fabsf(r1[c]) + fabsf(r2[c]);
    }

    // prefetch func row 3; its latency hides under the yl matmul
    float cur[S];
    LOAD_ROW(cur, nbp + 3 * S);

    // ---- yl = x + tanh([x,loc]@Wl + bl) -> park in SL_YL (retires loc, xr)
    {
        float a2[S];
        #pragma unroll
        for (int j = 0; j < S; j++) a2[j] = bl[j];
        MAT_R(a2, xr, Wl, 0);
        MAT_R(a2, loc, Wl, S);
        #pragma unroll
        for (int j = 0; j < S; j++) lds[SL_YL + j*64 + t] = xr[j] + ftanh(a2[j]);
    }

    // zero agg slot
    #pragma unroll
    for (int c = 0; c < S; c++) lds[SL_A + c*64 + t] = 0.0f;

    // ---- func rows 3..16: agg/act accumulate in LDS (RMW). live ~96 regs.
    #pragma unroll 1
    for (int k = 0; k < 14; k++) {
        float nxt[S];
        if (k < 13) { LOAD_ROW(nxt, nbp + (size_t)(4 + k) * S); }
        else {
            #pragma unroll
            for (int c = 0; c < S; c++) nxt[c] = 0.0f;
        }
        float tmp[S];
        #pragma unroll
        for (int j = 0; j < S; j++) tmp[j] = bm[j];
        MAT_R(tmp, cur, Wm, 0);
        #pragma unroll
        for (int j = 0; j < S; j++) lds[SL_A + j*64 + t] += fgelu(tmp[j]);
        #pragma unroll
        for (int c = 0; c < S; c++) lds[SL_ACT + c*64 + t] += fabsf(cur[c]);
        #pragma unroll
        for (int c = 0; c < S; c++) cur[c] = nxt[c];
    }

    // prefetch first 2 dist rows; latency hides under Wu+Wc (~6k cy)
    float dcur[S], dnx1[S];
    LOAD_ROW(dcur, nbp + 17 * S);
    LOAD_ROW(dnx1, nbp + 18 * S);

    // ---- h = x + tanh([x, agg/14]@Wu + bu); yf = h + DT*tanh(h@Wc + bc)
    float yfv[S];
    {
        float a2[S];
        #pragma unroll
        for (int j = 0; j < S; j++) a2[j] = bu[j];
        MAT_L(a2, SL_X, 1.0f, Wu, 0);
        MAT_L(a2, SL_A, (1.0f / 14.0f), Wu, S);
        float hv[S];
        #pragma unroll
        for (int j = 0; j < S; j++) hv[j] = lds[SL_X + j*64 + t] + ftanh(a2[j]);
        float a3[S];
        #pragma unroll
        for (int j = 0; j < S; j++) a3[j] = bc[j];
        MAT_R(a3, hv, Wc, 0);
        #pragma unroll
        for (int j = 0; j < S; j++) yfv[j] = hv[j] + DTC * ftanh(a3[j]);
    }

    // ---- dist rows 17..25 -> SL_A (agg dead; reuse) + act RMW. 2-deep prefetch.
    #pragma unroll
    for (int c = 0; c < S; c++) lds[SL_A + c*64 + t] = 0.0f;
    #pragma unroll 1
    for (int k = 0; k < 9; k++) {
        float nxt[S];
        if (k < 7) { LOAD_ROW(nxt, nbp + (size_t)(19 + k) * S); }
        else {
            #pragma unroll
            for (int c = 0; c < S; c++) nxt[c] = 0.0f;
        }
        #pragma unroll
        for (int c = 0; c < S; c++) lds[SL_A + c*64 + t] += dcur[c];
        #pragma unroll
        for (int c = 0; c < S; c++) lds[SL_ACT + c*64 + t] += fabsf(dcur[c]);
        #pragma unroll
        for (int c = 0; c < S; c++) { dcur[c] = dnx1[c]; dnx1[c] = nxt[c]; }
    }

    // ---- gate: layernorm(x) computed on the fly; act from LDS
    float g0v, g1w, g2v;
    {
        #pragma unroll
        for (int c = 0; c < S; c++) xr[c] = lds[SL_X + c*64 + t];
        float mu = 0.0f;
        #pragma unroll
        for (int c = 0; c < S; c++) mu += xr[c];
        mu *= (1.0f / S);
        float var = 0.0f;
        #pragma unroll
        for (int c = 0; c < S; c++) { float d = xr[c] - mu; var += d * d; }
        var *= (1.0f / S);
        float rstd = rsqrtf(var + 1e-5f);

        float g1v[8];
        #pragma unroll
        for (int u = 0; u < 8; u++) g1v[u] = gb1[u];
        #pragma unroll
        for (int i = 0; i < S; i++) {
            float a = (xr[i] - mu) * rstd * lng[i] + lnb[i];
            #pragma unroll
            for (int u = 0; u < 8; u++) g1v[u] += a * gW1[i*8 + u];
        }
        #pragma unroll
        for (int i = 0; i < S; i++) {
            float a = lds[SL_ACT + i*64 + t] * (1.0f / 26.0f);
            #pragma unroll
            for (int u = 0; u < 8; u++) g1v[u] += a * gW1[(S + i)*8 + u];
        }
        float l0 = gb2[0], l1 = gb2[1], l2 = gb2[2];
        #pragma unroll
        for (int u = 0; u < 8; u++) {
            float g = fgelu(g1v[u]);
            l0 += g * gW2[u*3 + 0];
            l1 += g * gW2[u*3 + 1];
            l2 += g * gW2[u*3 + 2];
        }
        float mx = fmaxf(l0, fmaxf(l1, l2));
        float e0 = __expf(l0 - mx), e1 = __expf(l1 - mx), e2 = __expf(l2 - mx);
        float rs = frcp(e0 + e1 + e2);
        g0v = e0 * rs; g1w = e1 * rs; g2v = e2 * rs;
    }

    // ---- CNF: xr holds x; update in place. dist streamed from SL_A (/9).
    #pragma unroll 1
    for (int it = 0; it < 3; it++) {
        float a2[S];
        #pragma unroll
        for (int j = 0; j < S; j++) a2[j] = bd[j];
        MAT_R(a2, xr, Wd, 0);
        MAT_L(a2, SL_A, (1.0f / 9.0f), Wd, S);
        #pragma unroll
        for (int j = 0; j < S; j++) xr[j] += DTC * ftanh(a2[j]);
    }

    // ---- combine + store: combined (B,32) then gate (B,3)
    {
        float4* op = reinterpret_cast<float4*>(out + (size_t)b * S);
        #pragma unroll
        for (int i = 0; i < 8; i++) {
            float c0 = g0v * lds[SL_YL + (4*i+0)*64 + t] + g1w * yfv[4*i+0] + g2v * xr[4*i+0];
            float c1 = g0v * lds[SL_YL + (4*i+1)*64 + t] + g1w * yfv[4*i+1] + g2v * xr[4*i+1];
            float c2 = g0v * lds[SL_YL + (4*i+2)*64 + t] + g1w * yfv[4*i+2] + g2v * xr[4*i+2];
            float c3 = g0v * lds[SL_YL + (4*i+3)*64 + t] + g1w * yfv[4*i+3] + g2v * xr[4*i+3];
            op[i] = make_float4(c0, c1, c2, c3);
        }
        float* gp = out + (size_t)B * S + (size_t)b * 3;
        gp[0] = g0v; gp[1] = g1w; gp[2] = g2v;
    }
}

extern "C" void kernel_launch(void* const* d_in, const int* in_sizes, int n_in,
                              void* d_out, int out_size, void* d_ws, size_t ws_size,
                              hipStream_t stream)
{
    const int B = in_sizes[0] / S;
    dim3 block(64);
    dim3 grid((B + 63) / 64);
    hipLaunchKernelGGL(moe_kernel, grid, block, 0, stream,
        (const float*)d_in[0],  (const float*)d_in[1],
        (const float*)d_in[2],  (const float*)d_in[3],
        (const float*)d_in[4],  (const float*)d_in[5],
        (const float*)d_in[6],  (const float*)d_in[7],
        (const float*)d_in[8],  (const float*)d_in[9],
        (const float*)d_in[10], (const float*)d_in[11],
        (const float*)d_in[12], (const float*)d_in[13],
        (const float*)d_in[14], (const float*)d_in[15],
        (const float*)d_in[16], (const float*)d_in[17],
        (float*)d_out, B);
}

// Round 5
// 1091.816 us; speedup vs baseline: 1.6284x; 1.3939x over previous
//
#include <hip/hip_runtime.h>

#define S 32
#define DTC 0.3f

// ---- LDS float-word offsets: weights (staged once), then per-thread state columns
#define W_L   0       // 2048 (64x32)
#define W_M   2048    // 1024 (32x32)
#define W_U   3072    // 2048
#define W_C   5120    // 1024
#define W_D   6144    // 2048 (64x32)
#define G_W1  8192    // 512  (64x8)
#define G_W2  8704    // 24   (8x3)
#define B_L   8736
#define B_M   8768
#define B_U   8800
#define B_C   8832
#define B_D   8864
#define LN_G  8896
#define LN_B  8928
#define G_B1  8960    // 8
#define G_B2  8992    // 3
// per-thread state columns: addr = slot + c*256 + tid  (bank = tid%32, 2-way free)
#define SL_ACT 9024
#define SL_AGG 17216
#define SL_YL  25408
#define LDSW   33600  // 131.25 KB -> 1 block/CU

__device__ __forceinline__ float frcp(float x) { return __builtin_amdgcn_rcpf(x); }

__device__ __forceinline__ float ftanh(float x) {
    float e = __expf(2.0f * x);
    return 1.0f - 2.0f * frcp(e + 1.0f);
}

__device__ __forceinline__ float fgelu(float x) {
    float t = ftanh(0.7978845608028654f * x * (1.0f + 0.044715f * x * x));
    return 0.5f * x * (1.0f + t);
}

#define LOAD_ROW(dst, ptr)                                           \
    {                                                                \
        const float4* rp_ = reinterpret_cast<const float4*>(ptr);    \
        _Pragma("unroll")                                            \
        for (int i_ = 0; i_ < 8; i_++) {                             \
            float4 v_ = rp_[i_];                                     \
            (dst)[4*i_+0] = v_.x; (dst)[4*i_+1] = v_.y;              \
            (dst)[4*i_+2] = v_.z; (dst)[4*i_+3] = v_.w;              \
        }                                                            \
    }

// acc[j] += a[i] * lds[wofs + i*32 + j]; wofs may be opaque (anti-LICM).
// Weight address is lane-uniform -> LDS broadcast, vectorizes to ds_read_b128.
#define MAT_W(acc, av, wofs)                                         \
    _Pragma("unroll")                                                \
    for (int i_ = 0; i_ < S; i_++) {                                 \
        float a_ = (av)[i_];                                         \
        _Pragma("unroll")                                            \
        for (int j_ = 0; j_ < S; j_++)                               \
            (acc)[j_] += a_ * lds[(wofs) + i_ * S + j_];             \
    }

#define STAGE(off, src, n)                                           \
    for (int i_ = t; i_ < (n); i_ += 256) lds[(off) + i_] = (src)[i_];

__global__ __launch_bounds__(256, 1) void moe_kernel(
    const float* __restrict__ cs,  const float* __restrict__ nb,
    const float* __restrict__ Wl,  const float* __restrict__ bl,
    const float* __restrict__ Wm,  const float* __restrict__ bm,
    const float* __restrict__ Wu,  const float* __restrict__ bu,
    const float* __restrict__ Wc,  const float* __restrict__ bc,
    const float* __restrict__ Wd,  const float* __restrict__ bd,
    const float* __restrict__ lng, const float* __restrict__ lnb,
    const float* __restrict__ gW1, const float* __restrict__ gb1,
    const float* __restrict__ gW2, const float* __restrict__ gb2,
    float* __restrict__ out, int B)
{
    __shared__ float lds[LDSW];
    const int t = threadIdx.x;
    int b = blockIdx.x * 256 + t;
    if (b >= B) b = B - 1;
    const float* nbp = nb + (size_t)b * (26 * S);

    // ---- stage weights/biases into LDS (coalesced, once per block)
    STAGE(W_L, Wl, 2048); STAGE(W_M, Wm, 1024); STAGE(W_U, Wu, 2048);
    STAGE(W_C, Wc, 1024); STAGE(W_D, Wd, 2048); STAGE(G_W1, gW1, 512);
    STAGE(G_W2, gW2, 24); STAGE(B_L, bl, 32);   STAGE(B_M, bm, 32);
    STAGE(B_U, bu, 32);   STAGE(B_C, bc, 32);   STAGE(B_D, bd, 32);
    STAGE(LN_G, lng, 32); STAGE(LN_B, lnb, 32); STAGE(G_B1, gb1, 8);
    STAGE(G_B2, gb2, 3);
    __syncthreads();

    // ---- startup: x + 3 local rows (latencies overlap)
    float x[S], r0[S], r1[S], r2[S];
    LOAD_ROW(x,  cs + (size_t)b * S);
    LOAD_ROW(r0, nbp + 0 * S);
    LOAD_ROW(r1, nbp + 1 * S);
    LOAD_ROW(r2, nbp + 2 * S);

    float loc[S];
    #pragma unroll
    for (int c = 0; c < S; c++) {
        loc[c] = (r0[c] + r1[c] + r2[c]) * (1.0f / 3.0f);
        lds[SL_ACT + c * 256 + t] = fabsf(r0[c]) + fabsf(r1[c]) + fabsf(r2[c]);
    }

    // prefetch func row 3 under the yl matmul
    float cur[S];
    LOAD_ROW(cur, nbp + 3 * S);

    // ---- yl = x + tanh([x,loc]@Wl + bl) -> park SL_YL (retires loc)
    {
        float a2[S];
        #pragma unroll
        for (int j = 0; j < S; j++) a2[j] = lds[B_L + j];
        MAT_W(a2, x, W_L);
        MAT_W(a2, loc, W_L + 1024);
        #pragma unroll
        for (int j = 0; j < S; j++) lds[SL_YL + j * 256 + t] = x[j] + ftanh(a2[j]);
    }

    // zero agg slot
    #pragma unroll
    for (int c = 0; c < S; c++) lds[SL_AGG + c * 256 + t] = 0.0f;

    // ---- func rows 3..16: agg += gelu(row@Wm+bm), act += |row|  (LDS RMW)
    #pragma unroll 1
    for (int k = 0; k < 14; k++) {
        float nxt[S];
        if (k < 13) { LOAD_ROW(nxt, nbp + (size_t)(4 + k) * S); }
        else {
            #pragma unroll
            for (int c = 0; c < S; c++) nxt[c] = 0.0f;
        }
        int wm = W_M;
        asm volatile("" : "+v"(wm));   // opaque offset: blocks invariant-load hoisting
        float tmp[S];
        #pragma unroll
        for (int j = 0; j < S; j++) tmp[j] = lds[B_M + j];
        MAT_W(tmp, cur, wm);
        #pragma unroll
        for (int j = 0; j < S; j++) lds[SL_AGG + j * 256 + t] += fgelu(tmp[j]);
        #pragma unroll
        for (int c = 0; c < S; c++) lds[SL_ACT + c * 256 + t] += fabsf(cur[c]);
        #pragma unroll
        for (int c = 0; c < S; c++) cur[c] = nxt[c];
    }

    // ---- h = x + tanh([x, agg/14]@Wu + bu); yf = h + DT*tanh(h@Wc + bc)
    float yfv[S];
    {
        float a2[S];
        #pragma unroll
        for (int j = 0; j < S; j++) a2[j] = lds[B_U + j];
        MAT_W(a2, x, W_U);
        #pragma unroll
        for (int i = 0; i < S; i++) {
            float a_ = lds[SL_AGG + i * 256 + t] * (1.0f / 14.0f);
            #pragma unroll
            for (int j = 0; j < S; j++) a2[j] += a_ * lds[W_U + 1024 + i * S + j];
        }
        float hv[S];
        #pragma unroll
        for (int j = 0; j < S; j++) hv[j] = x[j] + ftanh(a2[j]);
        float a3[S];
        #pragma unroll
        for (int j = 0; j < S; j++) a3[j] = lds[B_C + j];
        MAT_W(a3, hv, W_C);
        #pragma unroll
        for (int j = 0; j < S; j++) yfv[j] = hv[j] + DTC * ftanh(a3[j]);
    }

    // ---- dist rows 17..25 -> SL_AGG (agg dead, reuse) + act RMW, 2-deep prefetch
    #pragma unroll
    for (int c = 0; c < S; c++) lds[SL_AGG + c * 256 + t] = 0.0f;
    {
        float dcur[S], dnx1[S];
        LOAD_ROW(dcur, nbp + 17 * S);
        LOAD_ROW(dnx1, nbp + 18 * S);
        #pragma unroll 1
        for (int k = 0; k < 9; k++) {
            float nxt[S];
            if (k < 7) { LOAD_ROW(nxt, nbp + (size_t)(19 + k) * S); }
            else {
                #pragma unroll
                for (int c = 0; c < S; c++) nxt[c] = 0.0f;
            }
            #pragma unroll
            for (int c = 0; c < S; c++) lds[SL_AGG + c * 256 + t] += dcur[c];
            #pragma unroll
            for (int c = 0; c < S; c++) lds[SL_ACT + c * 256 + t] += fabsf(dcur[c]);
            #pragma unroll
            for (int c = 0; c < S; c++) { dcur[c] = dnx1[c]; dnx1[c] = nxt[c]; }
        }
    }

    // ---- gate
    float g0v, g1w, g2v;
    {
        float mu = 0.0f;
        #pragma unroll
        for (int c = 0; c < S; c++) mu += x[c];
        mu *= (1.0f / S);
        float var = 0.0f;
        #pragma unroll
        for (int c = 0; c < S; c++) { float d = x[c] - mu; var += d * d; }
        var *= (1.0f / S);
        float rstd = rsqrtf(var + 1e-5f);

        float g1v[8];
        #pragma unroll
        for (int u = 0; u < 8; u++) g1v[u] = lds[G_B1 + u];
        #pragma unroll
        for (int i = 0; i < S; i++) {
            float a = (x[i] - mu) * rstd * lds[LN_G + i] + lds[LN_B + i];
            #pragma unroll
            for (int u = 0; u < 8; u++) g1v[u] += a * lds[G_W1 + i * 8 + u];
        }
        #pragma unroll
        for (int i = 0; i < S; i++) {
            float a = lds[SL_ACT + i * 256 + t] * (1.0f / 26.0f);
            #pragma unroll
            for (int u = 0; u < 8; u++) g1v[u] += a * lds[G_W1 + (S + i) * 8 + u];
        }
        float l0 = lds[G_B2 + 0], l1 = lds[G_B2 + 1], l2 = lds[G_B2 + 2];
        #pragma unroll
        for (int u = 0; u < 8; u++) {
            float g = fgelu(g1v[u]);
            l0 += g * lds[G_W2 + u * 3 + 0];
            l1 += g * lds[G_W2 + u * 3 + 1];
            l2 += g * lds[G_W2 + u * 3 + 2];
        }
        float mx = fmaxf(l0, fmaxf(l1, l2));
        float e0 = __expf(l0 - mx), e1 = __expf(l1 - mx), e2 = __expf(l2 - mx);
        float rs = frcp(e0 + e1 + e2);
        g0v = e0 * rs; g1w = e1 * rs; g2v = e2 * rs;
    }

    // ---- CNF: x -> xt in place; dist streamed from SL_AGG (/9)
    #pragma unroll 1
    for (int it = 0; it < 3; it++) {
        int wd = W_D;
        asm volatile("" : "+v"(wd));   // opaque offset per iteration
        float a2[S];
        #pragma unroll
        for (int j = 0; j < S; j++) a2[j] = lds[B_D + j];
        MAT_W(a2, x, wd);
        #pragma unroll
        for (int i = 0; i < S; i++) {
            float a_ = lds[SL_AGG + i * 256 + t] * (1.0f / 9.0f);
            #pragma unroll
            for (int j = 0; j < S; j++) a2[j] += a_ * lds[wd + 1024 + i * S + j];
        }
        #pragma unroll
        for (int j = 0; j < S; j++) x[j] += DTC * ftanh(a2[j]);
    }

    // ---- combine + store: combined (B,32) then gate (B,3)
    {
        float4* op = reinterpret_cast<float4*>(out + (size_t)b * S);
        #pragma unroll
        for (int i = 0; i < 8; i++) {
            float c0 = g0v * lds[SL_YL + (4*i+0)*256 + t] + g1w * yfv[4*i+0] + g2v * x[4*i+0];
            float c1 = g0v * lds[SL_YL + (4*i+1)*256 + t] + g1w * yfv[4*i+1] + g2v * x[4*i+1];
            float c2 = g0v * lds[SL_YL + (4*i+2)*256 + t] + g1w * yfv[4*i+2] + g2v * x[4*i+2];
            float c3 = g0v * lds[SL_YL + (4*i+3)*256 + t] + g1w * yfv[4*i+3] + g2v * x[4*i+3];
            op[i] = make_float4(c0, c1, c2, c3);
        }
        float* gp = out + (size_t)B * S + (size_t)b * 3;
        gp[0] = g0v; gp[1] = g1w; gp[2] = g2v;
    }
}

extern "C" void kernel_launch(void* const* d_in, const int* in_sizes, int n_in,
                              void* d_out, int out_size, void* d_ws, size_t ws_size,
                              hipStream_t stream)
{
    const int B = in_sizes[0] / S;
    dim3 block(256);
    dim3 grid((B + 255) / 256);
    hipLaunchKernelGGL(moe_kernel, grid, block, 0, stream,
        (const float*)d_in[0],  (const float*)d_in[1],
        (const float*)d_in[2],  (const float*)d_in[3],
        (const float*)d_in[4],  (const float*)d_in[5],
        (const float*)d_in[6],  (const float*)d_in[7],
        (const float*)d_in[8],  (const float*)d_in[9],
        (const float*)d_in[10], (const float*)d_in[11],
        (const float*)d_in[12], (const float*)d_in[13],
        (const float*)d_in[14], (const float*)d_in[15],
        (const float*)d_in[16], (const float*)d_in[17],
        (float*)d_out, B);
}

// Round 6
// 965.999 us; speedup vs baseline: 1.8405x; 1.1302x over previous
//
#include <hip/hip_runtime.h>

#define S 32
#define DTC 0.3f

// Per-thread LDS state columns: addr = slot + c*64 + t  (t = lane 0..63).
// bank = (c*64+t)%32 = t%32 -> 2-way lane aliasing only (free, m136).
// 5 slots x 32ch x 64 lanes x 4B = 40 KB/block -> 4 blocks/CU (160 KB pool).
#define SL_X    0
#define SL_ACT  2048
#define SL_AGG  4096     // func agg, then reused for dist sum
#define SL_YL   6144
#define SL_YF   8192
#define LDSW    10240

__device__ __forceinline__ float frcp(float x) { return __builtin_amdgcn_rcpf(x); }

// tanh(x) = 1 - 2/(e^{2x}+1); exact saturation via exp->inf/0.
__device__ __forceinline__ float ftanh(float x) {
    float e = __expf(2.0f * x);
    return 1.0f - 2.0f * frcp(e + 1.0f);
}

// jax.nn.gelu(approximate=True)
__device__ __forceinline__ float fgelu(float x) {
    float t = ftanh(0.7978845608028654f * x * (1.0f + 0.044715f * x * x));
    return 0.5f * x * (1.0f + t);
}

#define LOAD_ROW(dst, ptr)                                           \
    {                                                                \
        const float4* rp_ = reinterpret_cast<const float4*>(ptr);    \
        _Pragma("unroll")                                            \
        for (int i_ = 0; i_ < 8; i_++) {                             \
            float4 v_ = rp_[i_];                                     \
            (dst)[4*i_+0] = v_.x; (dst)[4*i_+1] = v_.y;              \
            (dst)[4*i_+2] = v_.z; (dst)[4*i_+3] = v_.w;              \
        }                                                            \
    }

// acc[j] += a[i] * W[(row0+i)*32 + j] ; a in regs, W global (uniform -> s_load/SGPR)
#define MAT_R(acc, av, Wp, row0)                                     \
    _Pragma("unroll")                                                \
    for (int i_ = 0; i_ < S; i_++) {                                 \
        float a_ = (av)[i_];                                         \
        _Pragma("unroll")                                            \
        for (int j_ = 0; j_ < S; j_++)                               \
            (acc)[j_] += a_ * (Wp)[((row0)+i_)*S + j_];              \
    }

// same, but a[i] streamed from this thread's LDS column, scaled
#define MAT_LS(acc, slot, scale, Wp, row0)                           \
    _Pragma("unroll")                                                \
    for (int i_ = 0; i_ < S; i_++) {                                 \
        float a_ = lds[(slot) + i_*64 + t] * (scale);                \
        _Pragma("unroll")                                            \
        for (int j_ = 0; j_ < S; j_++)                               \
            (acc)[j_] += a_ * (Wp)[((row0)+i_)*S + j_];              \
    }

__global__ __launch_bounds__(64, 1) void moe_kernel(
    const float* __restrict__ cs,  const float* __restrict__ nb,
    const float* __restrict__ Wl,  const float* __restrict__ bl,
    const float* __restrict__ Wm,  const float* __restrict__ bm,
    const float* __restrict__ Wu,  const float* __restrict__ bu,
    const float* __restrict__ Wc,  const float* __restrict__ bc,
    const float* __restrict__ Wd,  const float* __restrict__ bd,
    const float* __restrict__ lng, const float* __restrict__ lnb,
    const float* __restrict__ gW1, const float* __restrict__ gb1,
    const float* __restrict__ gW2, const float* __restrict__ gb2,
    float* __restrict__ out, int B)
{
    __shared__ float lds[LDSW];
    const int t = threadIdx.x;
    int b = blockIdx.x * 64 + t;
    if (b >= B) b = B - 1;   // B%64==0 here; clamp benign
    const float* nbp = nb + (size_t)b * (26 * S);

    // ---- Phase 1: local rows 0..2 -> loc (regs), act -> LDS
    float loc[S];
    {
        float r0[S], r1[S], r2[S];
        LOAD_ROW(r0, nbp + 0 * S);
        LOAD_ROW(r1, nbp + 1 * S);
        LOAD_ROW(r2, nbp + 2 * S);
        #pragma unroll
        for (int c = 0; c < S; c++) {
            loc[c] = (r0[c] + r1[c] + r2[c]) * (1.0f / 3.0f);
            lds[SL_ACT + c * 64 + t] = fabsf(r0[c]) + fabsf(r1[c]) + fabsf(r2[c]);
        }
    }

    // ---- Phase 2: load x -> park; yl = x + tanh([x,loc]@Wl+bl) -> SL_YL
    {
        float x[S];
        LOAD_ROW(x, cs + (size_t)b * S);
        #pragma unroll
        for (int c = 0; c < S; c++) lds[SL_X + c * 64 + t] = x[c];
        float acc[S];
        #pragma unroll
        for (int j = 0; j < S; j++) acc[j] = bl[j];
        MAT_R(acc, x, Wl, 0);
        MAT_R(acc, loc, Wl, S);
        #pragma unroll
        for (int j = 0; j < S; j++) lds[SL_YL + j * 64 + t] = x[j] + ftanh(acc[j]);
    }
    // x, loc retired from regs; x lives in SL_X.

    // zero agg slot
    #pragma unroll
    for (int c = 0; c < S; c++) lds[SL_AGG + c * 64 + t] = 0.0f;

    // ---- Phase 3: func rows 3..16. Body live: cur(32)+nxt(32)+tmp(32)+misc ~110.
    {
        float cur[S];
        LOAD_ROW(cur, nbp + 3 * S);
        #pragma unroll 1
        for (int k = 0; k < 14; k++) {
            float nxt[S];
            if (k < 13) { LOAD_ROW(nxt, nbp + (size_t)(4 + k) * S); }
            else {
                #pragma unroll
                for (int c = 0; c < S; c++) nxt[c] = 0.0f;
            }
            float tmp[S];
            #pragma unroll
            for (int j = 0; j < S; j++) tmp[j] = bm[j];
            MAT_R(tmp, cur, Wm, 0);
            #pragma unroll
            for (int j = 0; j < S; j++) lds[SL_AGG + j * 64 + t] += fgelu(tmp[j]);
            #pragma unroll
            for (int c = 0; c < S; c++) lds[SL_ACT + c * 64 + t] += fabsf(cur[c]);
            #pragma unroll
            for (int c = 0; c < S; c++) cur[c] = nxt[c];
        }
    }

    // ---- Phase 4: h = x + tanh([x, agg/14]@Wu+bu); yf = h + DT*tanh(h@Wc+bc) -> SL_YF
    {
        float acc[S];
        #pragma unroll
        for (int j = 0; j < S; j++) acc[j] = bu[j];
        MAT_LS(acc, SL_X, 1.0f, Wu, 0);
        MAT_LS(acc, SL_AGG, (1.0f / 14.0f), Wu, S);
        float h[S];
        #pragma unroll
        for (int j = 0; j < S; j++) h[j] = lds[SL_X + j * 64 + t] + ftanh(acc[j]);
        float a2[S];
        #pragma unroll
        for (int j = 0; j < S; j++) a2[j] = bc[j];
        MAT_R(a2, h, Wc, 0);
        #pragma unroll
        for (int j = 0; j < S; j++) lds[SL_YF + j * 64 + t] = h[j] + DTC * ftanh(a2[j]);
    }

    // ---- Phase 5: dist rows 17..25 -> SL_AGG (reuse) + act. 2-deep prefetch.
    #pragma unroll
    for (int c = 0; c < S; c++) lds[SL_AGG + c * 64 + t] = 0.0f;
    {
        float dcur[S], dnx1[S];
        LOAD_ROW(dcur, nbp + 17 * S);
        LOAD_ROW(dnx1, nbp + 18 * S);
        #pragma unroll 1
        for (int k = 0; k < 9; k++) {
            float nxt[S];
            if (k < 7) { LOAD_ROW(nxt, nbp + (size_t)(19 + k) * S); }
            else {
                #pragma unroll
                for (int c = 0; c < S; c++) nxt[c] = 0.0f;
            }
            #pragma unroll
            for (int c = 0; c < S; c++) {
                lds[SL_AGG + c * 64 + t] += dcur[c];
                lds[SL_ACT + c * 64 + t] += fabsf(dcur[c]);
            }
            #pragma unroll
            for (int c = 0; c < S; c++) { dcur[c] = dnx1[c]; dnx1[c] = nxt[c]; }
        }
    }

    // ---- Phase 6: gate. x back into regs (needed for CNF anyway).
    float xr[S];
    #pragma unroll
    for (int c = 0; c < S; c++) xr[c] = lds[SL_X + c * 64 + t];
    float g0v, g1w, g2v;
    {
        float mu = 0.0f;
        #pragma unroll
        for (int c = 0; c < S; c++) mu += xr[c];
        mu *= (1.0f / S);
        float var = 0.0f;
        #pragma unroll
        for (int c = 0; c < S; c++) { float d = xr[c] - mu; var += d * d; }
        var *= (1.0f / S);
        float rstd = rsqrtf(var + 1e-5f);

        float g1v[8];
        #pragma unroll
        for (int u = 0; u < 8; u++) g1v[u] = gb1[u];
        #pragma unroll
        for (int i = 0; i < S; i++) {
            float a = (xr[i] - mu) * rstd * lng[i] + lnb[i];
            #pragma unroll
            for (int u = 0; u < 8; u++) g1v[u] += a * gW1[i * 8 + u];
        }
        #pragma unroll
        for (int i = 0; i < S; i++) {
            float a = lds[SL_ACT + i * 64 + t] * (1.0f / 26.0f);
            #pragma unroll
            for (int u = 0; u < 8; u++) g1v[u] += a * gW1[(S + i) * 8 + u];
        }
        float l0 = gb2[0], l1 = gb2[1], l2 = gb2[2];
        #pragma unroll
        for (int u = 0; u < 8; u++) {
            float g = fgelu(g1v[u]);
            l0 += g * gW2[u * 3 + 0];
            l1 += g * gW2[u * 3 + 1];
            l2 += g * gW2[u * 3 + 2];
        }
        float mx = fmaxf(l0, fmaxf(l1, l2));
        float e0 = __expf(l0 - mx), e1 = __expf(l1 - mx), e2 = __expf(l2 - mx);
        float rs = frcp(e0 + e1 + e2);
        g0v = e0 * rs; g1w = e1 * rs; g2v = e2 * rs;
    }

    // ---- Phase 7: CNF on xr (3 steps); dist streamed from SL_AGG (/9).
    // Body live: xr(32)+acc(32)+misc ~75.
    #pragma unroll 1
    for (int it = 0; it < 3; it++) {
        float acc[S];
        #pragma unroll
        for (int j = 0; j < S; j++) acc[j] = bd[j];
        MAT_R(acc, xr, Wd, 0);
        MAT_LS(acc, SL_AGG, (1.0f / 9.0f), Wd, S);
        #pragma unroll
        for (int j = 0; j < S; j++) xr[j] += DTC * ftanh(acc[j]);
    }

    // ---- combine + store: combined (B,32) then gate (B,3)
    {
        float4* op = reinterpret_cast<float4*>(out + (size_t)b * S);
        #pragma unroll
        for (int i = 0; i < 8; i++) {
            float c0 = g0v * lds[SL_YL + (4*i+0)*64 + t] + g1w * lds[SL_YF + (4*i+0)*64 + t] + g2v * xr[4*i+0];
            float c1 = g0v * lds[SL_YL + (4*i+1)*64 + t] + g1w * lds[SL_YF + (4*i+1)*64 + t] + g2v * xr[4*i+1];
            float c2 = g0v * lds[SL_YL + (4*i+2)*64 + t] + g1w * lds[SL_YF + (4*i+2)*64 + t] + g2v * xr[4*i+2];
            float c3 = g0v * lds[SL_YL + (4*i+3)*64 + t] + g1w * lds[SL_YF + (4*i+3)*64 + t] + g2v * xr[4*i+3];
            op[i] = make_float4(c0, c1, c2, c3);
        }
        float* gp = out + (size_t)B * S + (size_t)b * 3;
        gp[0] = g0v; gp[1] = g1w; gp[2] = g2v;
    }
}

extern "C" void kernel_launch(void* const* d_in, const int* in_sizes, int n_in,
                              void* d_out, int out_size, void* d_ws, size_t ws_size,
                              hipStream_t stream)
{
    const int B = in_sizes[0] / S;
    dim3 block(64);
    dim3 grid((B + 63) / 64);
    hipLaunchKernelGGL(moe_kernel, grid, block, 0, stream,
        (const float*)d_in[0],  (const float*)d_in[1],
        (const float*)d_in[2],  (const float*)d_in[3],
        (const float*)d_in[4],  (const float*)d_in[5],
        (const float*)d_in[6],  (const float*)d_in[7],
        (const float*)d_in[8],  (const float*)d_in[9],
        (const float*)d_in[10], (const float*)d_in[11],
        (const float*)d_in[12], (const float*)d_in[13],
        (const float*)d_in[14], (const float*)d_in[15],
        (const float*)d_in[16], (const float*)d_in[17],
        (float*)d_out, B);
}

// Round 7
// 56.070 us; speedup vs baseline: 31.7091x; 17.2283x over previous
//
#include <hip/hip_runtime.h>

typedef float f32x4 __attribute__((ext_vector_type(4)));
typedef __bf16 bf16x8 __attribute__((ext_vector_type(8)));
typedef unsigned short ushort8 __attribute__((ext_vector_type(8)));

#define S 32
#define DTC 0.3f

__device__ __forceinline__ float frcp(float x) { return __builtin_amdgcn_rcpf(x); }

// tanh(x) = 1 - 2/(e^{2x}+1); exact saturation via exp->inf/0.
__device__ __forceinline__ float ftanh(float x) {
    float e = __expf(2.0f * x);
    return 1.0f - 2.0f * frcp(e + 1.0f);
}

// jax.nn.gelu(approximate=True)
__device__ __forceinline__ float fgelu(float x) {
    float t = ftanh(0.7978845608028654f * x * (1.0f + 0.044715f * x * x));
    return 0.5f * x * (1.0f + t);
}

// fp32 -> bf16 bits, round-to-nearest-even
__device__ __forceinline__ unsigned short f2bf(float f) {
    unsigned int u = __builtin_bit_cast(unsigned int, f);
    u += 0x7fffu + ((u >> 16) & 1u);
    return (unsigned short)(u >> 16);
}

union ABFrag { ushort8 u; bf16x8 v; };

// load 8 consecutive floats (16B-aligned) as two float4
__device__ __forceinline__ void load_row8(const float* p, float out[8]) {
    const float4* q = reinterpret_cast<const float4*>(p);
    float4 a = q[0], b = q[1];
    out[0]=a.x; out[1]=a.y; out[2]=a.z; out[3]=a.w;
    out[4]=b.x; out[5]=b.y; out[6]=b.z; out[7]=b.w;
}

__device__ __forceinline__ ABFrag pack8(const float f[8]) {
    ABFrag r;
    #pragma unroll
    for (int e = 0; e < 8; e++) r.u[e] = f2bf(f[e]);
    return r;
}

// B-frag: W row-major (K x 32); k = kbase + e (kbase includes 8*lg), fixed col
__device__ __forceinline__ ABFrag load_w(const float* W, int kbase, int col) {
    ABFrag r;
    #pragma unroll
    for (int e = 0; e < 8; e++) r.u[e] = f2bf(W[(kbase + e) * S + col]);
    return r;
}

#define MFMA(a, b, c) __builtin_amdgcn_mfma_f32_16x16x32_bf16((a), (b), (c), 0, 0, 0)

// C-layout (2 n-tiles x 4 rows, fp32) -> A-frag via per-wave LDS bounce
#define BOUNCE(dstFrag, srcC, scale)                                            \
    {                                                                           \
        _Pragma("unroll")                                                       \
        for (int nt_ = 0; nt_ < 2; nt_++)                                       \
            _Pragma("unroll")                                                   \
            for (int r_ = 0; r_ < 4; r_++)                                      \
                lbuf[wid][(4*lg + r_)*40 + lr + 16*nt_] =                       \
                    f2bf((srcC)[nt_][r_] * (scale));                            \
        __syncthreads();                                                        \
        (dstFrag).u = *(const ushort8*)&lbuf[wid][lr*40 + 8*lg];                \
        __syncthreads();                                                        \
    }

__global__ __launch_bounds__(256, 1) void moe_kernel(
    const float* __restrict__ cs,  const float* __restrict__ nb,
    const float* __restrict__ Wl,  const float* __restrict__ bl,
    const float* __restrict__ Wm,  const float* __restrict__ bm,
    const float* __restrict__ Wu,  const float* __restrict__ bu,
    const float* __restrict__ Wc,  const float* __restrict__ bc,
    const float* __restrict__ Wd,  const float* __restrict__ bd,
    const float* __restrict__ lng, const float* __restrict__ lnb,
    const float* __restrict__ gW1, const float* __restrict__ gb1,
    const float* __restrict__ gW2, const float* __restrict__ gb2,
    float* __restrict__ out, int B)
{
    __shared__ __align__(16) unsigned short lbuf[4][16 * 40]; // per-wave bounce
    __shared__ float gbuf[4][16][4];                          // per-wave gates

    const int tid = threadIdx.x;
    const int wid = tid >> 6, lane = tid & 63;
    const int lr = lane & 15, lg = lane >> 4;
    const int b0 = (blockIdx.x * 4 + wid) * 16;
    if (b0 >= B) return;

    // ---- weight B-frags: 16 frags = 64 VGPRs, held whole kernel
    ABFrag WlB[2][2], WuB[2][2], WdB[2][2], WmB[2], WcB[2];
    #pragma unroll
    for (int nt = 0; nt < 2; nt++) {
        const int col = lr + 16 * nt;
        #pragma unroll
        for (int kt = 0; kt < 2; kt++) {
            WlB[kt][nt] = load_w(Wl, kt * 32 + 8 * lg, col);
            WuB[kt][nt] = load_w(Wu, kt * 32 + 8 * lg, col);
            WdB[kt][nt] = load_w(Wd, kt * 32 + 8 * lg, col);
        }
        WmB[nt] = load_w(Wm, 8 * lg, col);
        WcB[nt] = load_w(Wc, 8 * lg, col);
    }
    // biases in C-layout (per n-tile, col = lr+16nt, same for all 4 rows)
    const float blc[2] = { bl[lr], bl[lr + 16] };
    const float bmc[2] = { bm[lr], bm[lr + 16] };
    const float buc[2] = { bu[lr], bu[lr + 16] };
    const float bcc[2] = { bc[lr], bc[lr + 16] };
    const float bdc[2] = { bd[lr], bd[lr + 16] };

    // ---- x: A-layout (keep fp32 for LN) and C-layout (residuals)
    float xf[8];
    load_row8(cs + (size_t)(b0 + lr) * S + 8 * lg, xf);
    ABFrag xA = pack8(xf);
    float xC[2][4];
    #pragma unroll
    for (int nt = 0; nt < 2; nt++)
        #pragma unroll
        for (int r = 0; r < 4; r++)
            xC[nt][r] = cs[(size_t)(b0 + 4 * lg + r) * S + lr + 16 * nt];

    float act[8];
    #pragma unroll
    for (int e = 0; e < 8; e++) act[e] = 0.0f;

    // ---- local rows 0..2 -> loc (fp32 avg) ; act accum
    float locf[8];
    #pragma unroll
    for (int e = 0; e < 8; e++) locf[e] = 0.0f;
    #pragma unroll
    for (int k = 0; k < 3; k++) {
        float rf[8];
        load_row8(nb + ((size_t)(b0 + lr) * 26 + k) * S + 8 * lg, rf);
        #pragma unroll
        for (int e = 0; e < 8; e++) { locf[e] += rf[e]; act[e] += fabsf(rf[e]); }
    }
    #pragma unroll
    for (int e = 0; e < 8; e++) locf[e] *= (1.0f / 3.0f);
    ABFrag locA = pack8(locf);

    // ---- yl = x + tanh([x,loc]@Wl + bl)   (C-layout)
    float ylC[2][4];
    #pragma unroll
    for (int nt = 0; nt < 2; nt++) {
        f32x4 acc = { blc[nt], blc[nt], blc[nt], blc[nt] };
        acc = MFMA(xA.v,   WlB[0][nt].v, acc);
        acc = MFMA(locA.v, WlB[1][nt].v, acc);
        #pragma unroll
        for (int r = 0; r < 4; r++) ylC[nt][r] = xC[nt][r] + ftanh(acc[r]);
    }

    // ---- func rows 3..16: agg += gelu(row@Wm + bm)   (C-layout accum)
    float aggC[2][4];
    #pragma unroll
    for (int nt = 0; nt < 2; nt++)
        #pragma unroll
        for (int r = 0; r < 4; r++) aggC[nt][r] = 0.0f;
    #pragma unroll 2
    for (int k = 0; k < 14; k++) {
        float rf[8];
        load_row8(nb + ((size_t)(b0 + lr) * 26 + 3 + k) * S + 8 * lg, rf);
        #pragma unroll
        for (int e = 0; e < 8; e++) act[e] += fabsf(rf[e]);
        ABFrag a = pack8(rf);
        #pragma unroll
        for (int nt = 0; nt < 2; nt++) {
            f32x4 am = { bmc[nt], bmc[nt], bmc[nt], bmc[nt] };
            am = MFMA(a.v, WmB[nt].v, am);
            #pragma unroll
            for (int r = 0; r < 4; r++) aggC[nt][r] += fgelu(am[r]);
        }
    }

    // ---- agg/14 -> A-frag (transpose bounce)
    ABFrag aggA;
    BOUNCE(aggA, aggC, (1.0f / 14.0f));

    // ---- h = x + tanh([x,agg]@Wu + bu); yf = h + DT*tanh(h@Wc + bc)
    float hC[2][4], yfC[2][4];
    #pragma unroll
    for (int nt = 0; nt < 2; nt++) {
        f32x4 acc = { buc[nt], buc[nt], buc[nt], buc[nt] };
        acc = MFMA(xA.v,   WuB[0][nt].v, acc);
        acc = MFMA(aggA.v, WuB[1][nt].v, acc);
        #pragma unroll
        for (int r = 0; r < 4; r++) hC[nt][r] = xC[nt][r] + ftanh(acc[r]);
    }
    ABFrag hA;
    BOUNCE(hA, hC, 1.0f);
    #pragma unroll
    for (int nt = 0; nt < 2; nt++) {
        f32x4 acc = { bcc[nt], bcc[nt], bcc[nt], bcc[nt] };
        acc = MFMA(hA.v, WcB[nt].v, acc);
        #pragma unroll
        for (int r = 0; r < 4; r++) yfC[nt][r] = hC[nt][r] + DTC * ftanh(acc[r]);
    }

    // ---- dist rows 17..25 -> fp32 avg ; act accum
    float distf[8];
    #pragma unroll
    for (int e = 0; e < 8; e++) distf[e] = 0.0f;
    #pragma unroll 3
    for (int k = 0; k < 9; k++) {
        float rf[8];
        load_row8(nb + ((size_t)(b0 + lr) * 26 + 17 + k) * S + 8 * lg, rf);
        #pragma unroll
        for (int e = 0; e < 8; e++) { distf[e] += rf[e]; act[e] += fabsf(rf[e]); }
    }
    #pragma unroll
    for (int e = 0; e < 8; e++) distf[e] *= (1.0f / 9.0f);
    ABFrag distA = pack8(distf);

    // ---- gate (fp32, wave reductions over lg groups)
    {
        float s = 0.0f;
        #pragma unroll
        for (int e = 0; e < 8; e++) s += xf[e];
        s += __shfl_xor(s, 16); s += __shfl_xor(s, 32);
        const float mu = s * (1.0f / S);
        float v = 0.0f;
        #pragma unroll
        for (int e = 0; e < 8; e++) { float d = xf[e] - mu; v += d * d; }
        v += __shfl_xor(v, 16); v += __shfl_xor(v, 32);
        const float rstd = rsqrtf(v * (1.0f / S) + 1e-5f);

        float g1v[8];
        #pragma unroll
        for (int u = 0; u < 8; u++) g1v[u] = 0.0f;
        #pragma unroll
        for (int e = 0; e < 8; e++) {
            const int i = 8 * lg + e;
            const float a  = (xf[e] - mu) * rstd * lng[i] + lnb[i];
            const float ac = act[e] * (1.0f / 26.0f);
            #pragma unroll
            for (int u = 0; u < 8; u++)
                g1v[u] += a * gW1[i * 8 + u] + ac * gW1[(S + i) * 8 + u];
        }
        float l0 = gb2[0], l1 = gb2[1], l2 = gb2[2];
        #pragma unroll
        for (int u = 0; u < 8; u++) {
            float gt = g1v[u];
            gt += __shfl_xor(gt, 16); gt += __shfl_xor(gt, 32);
            const float g = fgelu(gt + gb1[u]);
            l0 += g * gW2[u * 3 + 0];
            l1 += g * gW2[u * 3 + 1];
            l2 += g * gW2[u * 3 + 2];
        }
        const float mx = fmaxf(l0, fmaxf(l1, l2));
        const float e0 = __expf(l0 - mx), e1 = __expf(l1 - mx), e2 = __expf(l2 - mx);
        const float rs = frcp(e0 + e1 + e2);
        if (lg == 0) {
            gbuf[wid][lr][0] = e0 * rs;
            gbuf[wid][lr][1] = e1 * rs;
            gbuf[wid][lr][2] = e2 * rs;
        }
    }
    __syncthreads();

    // ---- CNF: 3 steps; xt in C-layout + A-frag (re-bounced per step)
    float xtC[2][4];
    #pragma unroll
    for (int nt = 0; nt < 2; nt++)
        #pragma unroll
        for (int r = 0; r < 4; r++) xtC[nt][r] = xC[nt][r];
    ABFrag xtA = xA;
    #pragma unroll 1
    for (int it = 0; it < 3; it++) {
        #pragma unroll
        for (int nt = 0; nt < 2; nt++) {
            f32x4 acc = { bdc[nt], bdc[nt], bdc[nt], bdc[nt] };
            acc = MFMA(xtA.v,  WdB[0][nt].v, acc);
            acc = MFMA(distA.v, WdB[1][nt].v, acc);
            #pragma unroll
            for (int r = 0; r < 4; r++) xtC[nt][r] += DTC * ftanh(acc[r]);
        }
        if (it < 2) { BOUNCE(xtA, xtC, 1.0f); }
    }

    // ---- combine + store (C-layout rows coalesced)
    #pragma unroll
    for (int nt = 0; nt < 2; nt++)
        #pragma unroll
        for (int r = 0; r < 4; r++) {
            const int brow = 4 * lg + r;
            const float g0 = gbuf[wid][brow][0];
            const float g1 = gbuf[wid][brow][1];
            const float g2 = gbuf[wid][brow][2];
            out[(size_t)(b0 + brow) * S + lr + 16 * nt] =
                g0 * ylC[nt][r] + g1 * yfC[nt][r] + g2 * xtC[nt][r];
        }
    if (lg == 0) {
        float* gp = out + (size_t)B * S + (size_t)(b0 + lr) * 3;
        gp[0] = gbuf[wid][lr][0];
        gp[1] = gbuf[wid][lr][1];
        gp[2] = gbuf[wid][lr][2];
    }
}

extern "C" void kernel_launch(void* const* d_in, const int* in_sizes, int n_in,
                              void* d_out, int out_size, void* d_ws, size_t ws_size,
                              hipStream_t stream)
{
    const int B = in_sizes[0] / S;
    dim3 block(256);
    dim3 grid((B + 63) / 64);   // 64 batch per block (4 waves x 16)
    hipLaunchKernelGGL(moe_kernel, grid, block, 0, stream,
        (const float*)d_in[0],  (const float*)d_in[1],
        (const float*)d_in[2],  (const float*)d_in[3],
        (const float*)d_in[4],  (const float*)d_in[5],
        (const float*)d_in[6],  (const float*)d_in[7],
        (const float*)d_in[8],  (const float*)d_in[9],
        (const float*)d_in[10], (const float*)d_in[11],
        (const float*)d_in[12], (const float*)d_in[13],
        (const float*)d_in[14], (const float*)d_in[15],
        (const float*)d_in[16], (const float*)d_in[17],
        (float*)d_out, B);
}

// Round 8
// 49.485 us; speedup vs baseline: 35.9287x; 1.1331x over previous
//
#include <hip/hip_runtime.h>

typedef float f32x4 __attribute__((ext_vector_type(4)));
typedef __bf16 bf16x8 __attribute__((ext_vector_type(8)));

#define S 32
#define DTC 0.3f

__device__ __forceinline__ float frcp(float x) { return __builtin_amdgcn_rcpf(x); }

// tanh(x) = 1 - 2/(e^{2x}+1); exact saturation via exp->inf/0.
__device__ __forceinline__ float ftanh(float x) {
    float e = __expf(2.0f * x);
    return 1.0f - 2.0f * frcp(e + 1.0f);
}

// jax.nn.gelu(approximate=True)
__device__ __forceinline__ float fgelu(float x) {
    float t = ftanh(0.7978845608028654f * x * (1.0f + 0.044715f * x * x));
    return 0.5f * x * (1.0f + t);
}

// wave-local LDS ordering: drain own DS ops; block compiler reordering.
#define WAVE_LDS_FENCE() asm volatile("s_waitcnt lgkmcnt(0)" ::: "memory")
#define REORDER_FENCE()  asm volatile("" ::: "memory")

union ABFrag { bf16x8 v; };

// load 8 consecutive floats (16B-aligned) as two float4
__device__ __forceinline__ void load_row8(const float* p, float out[8]) {
    const float4* q = reinterpret_cast<const float4*>(p);
    float4 a = q[0], b = q[1];
    out[0]=a.x; out[1]=a.y; out[2]=a.z; out[3]=a.w;
    out[4]=b.x; out[5]=b.y; out[6]=b.z; out[7]=b.w;
}

__device__ __forceinline__ ABFrag pack8(const float f[8]) {
    ABFrag r;
    #pragma unroll
    for (int e = 0; e < 8; e++) r.v[e] = (__bf16)f[e];   // compiler: v_cvt_pk_bf16_f32
    return r;
}

// B-frag: W row-major (K x 32); k = kbase + e (kbase includes 8*lg), fixed col
__device__ __forceinline__ ABFrag load_w(const float* W, int kbase, int col) {
    ABFrag r;
    #pragma unroll
    for (int e = 0; e < 8; e++) r.v[e] = (__bf16)W[(kbase + e) * S + col];
    return r;
}

#define MFMA(a, b, c) __builtin_amdgcn_mfma_f32_16x16x32_bf16((a), (b), (c), 0, 0, 0)

// C-layout (2 n-tiles x 4 rows, fp32) -> A-frag via per-WAVE LDS bounce.
// Per-wave buffer + in-order DS pipe: lgkmcnt(0) before read (RAW),
// reorder fence after read (WAR vs next bounce's writes).
#define BOUNCE(dstFrag, srcC, scale)                                            \
    {                                                                           \
        _Pragma("unroll")                                                       \
        for (int nt_ = 0; nt_ < 2; nt_++)                                       \
            _Pragma("unroll")                                                   \
            for (int r_ = 0; r_ < 4; r_++)                                      \
                lbuf[wid][(4*lg + r_)*40 + lr + 16*nt_] =                       \
                    (__bf16)((srcC)[nt_][r_] * (scale));                        \
        WAVE_LDS_FENCE();                                                       \
        (dstFrag).v = *(const bf16x8*)&lbuf[wid][lr*40 + 8*lg];                 \
        REORDER_FENCE();                                                        \
    }

__global__ __launch_bounds__(256, 2) void moe_kernel(
    const float* __restrict__ cs,  const float* __restrict__ nb,
    const float* __restrict__ Wl,  const float* __restrict__ bl,
    const float* __restrict__ Wm,  const float* __restrict__ bm,
    const float* __restrict__ Wu,  const float* __restrict__ bu,
    const float* __restrict__ Wc,  const float* __restrict__ bc,
    const float* __restrict__ Wd,  const float* __restrict__ bd,
    const float* __restrict__ lng, const float* __restrict__ lnb,
    const float* __restrict__ gW1, const float* __restrict__ gb1,
    const float* __restrict__ gW2, const float* __restrict__ gb2,
    float* __restrict__ out, int B)
{
    __shared__ __align__(16) __bf16 lbuf[4][16 * 40]; // per-wave bounce
    __shared__ float gbuf[4][16][4];                  // per-wave gates

    const int tid = threadIdx.x;
    const int wid = tid >> 6, lane = tid & 63;
    const int lr = lane & 15, lg = lane >> 4;
    const int b0 = (blockIdx.x * 4 + wid) * 16;
    if (b0 >= B) return;

    // ---- weight B-frags: 16 frags = 64 VGPRs, held whole kernel
    ABFrag WlB[2][2], WuB[2][2], WdB[2][2], WmB[2], WcB[2];
    #pragma unroll
    for (int nt = 0; nt < 2; nt++) {
        const int col = lr + 16 * nt;
        #pragma unroll
        for (int kt = 0; kt < 2; kt++) {
            WlB[kt][nt] = load_w(Wl, kt * 32 + 8 * lg, col);
            WuB[kt][nt] = load_w(Wu, kt * 32 + 8 * lg, col);
            WdB[kt][nt] = load_w(Wd, kt * 32 + 8 * lg, col);
        }
        WmB[nt] = load_w(Wm, 8 * lg, col);
        WcB[nt] = load_w(Wc, 8 * lg, col);
    }
    // biases in C-layout (per n-tile, col = lr+16nt, same for all 4 rows)
    const float blc[2] = { bl[lr], bl[lr + 16] };
    const float bmc[2] = { bm[lr], bm[lr + 16] };
    const float buc[2] = { bu[lr], bu[lr + 16] };
    const float bcc[2] = { bc[lr], bc[lr + 16] };
    const float bdc[2] = { bd[lr], bd[lr + 16] };

    // ---- x: A-layout (keep fp32 for LN) and C-layout (residuals)
    float xf[8];
    load_row8(cs + (size_t)(b0 + lr) * S + 8 * lg, xf);
    ABFrag xA = pack8(xf);
    float xC[2][4];
    #pragma unroll
    for (int nt = 0; nt < 2; nt++)
        #pragma unroll
        for (int r = 0; r < 4; r++)
            xC[nt][r] = cs[(size_t)(b0 + 4 * lg + r) * S + lr + 16 * nt];

    float act[8];
    #pragma unroll
    for (int e = 0; e < 8; e++) act[e] = 0.0f;

    // ---- local rows 0..2 -> loc (fp32 avg) ; act accum
    float locf[8];
    #pragma unroll
    for (int e = 0; e < 8; e++) locf[e] = 0.0f;
    #pragma unroll
    for (int k = 0; k < 3; k++) {
        float rf[8];
        load_row8(nb + ((size_t)(b0 + lr) * 26 + k) * S + 8 * lg, rf);
        #pragma unroll
        for (int e = 0; e < 8; e++) { locf[e] += rf[e]; act[e] += fabsf(rf[e]); }
    }
    #pragma unroll
    for (int e = 0; e < 8; e++) locf[e] *= (1.0f / 3.0f);
    ABFrag locA = pack8(locf);

    // ---- yl = x + tanh([x,loc]@Wl + bl)   (C-layout)
    float ylC[2][4];
    #pragma unroll
    for (int nt = 0; nt < 2; nt++) {
        f32x4 acc = { blc[nt], blc[nt], blc[nt], blc[nt] };
        acc = MFMA(xA.v,   WlB[0][nt].v, acc);
        acc = MFMA(locA.v, WlB[1][nt].v, acc);
        #pragma unroll
        for (int r = 0; r < 4; r++) ylC[nt][r] = xC[nt][r] + ftanh(acc[r]);
    }

    // ---- func rows 3..16: agg += gelu(row@Wm + bm)   (C-layout accum)
    float aggC[2][4];
    #pragma unroll
    for (int nt = 0; nt < 2; nt++)
        #pragma unroll
        for (int r = 0; r < 4; r++) aggC[nt][r] = 0.0f;
    #pragma unroll 2
    for (int k = 0; k < 14; k++) {
        float rf[8];
        load_row8(nb + ((size_t)(b0 + lr) * 26 + 3 + k) * S + 8 * lg, rf);
        #pragma unroll
        for (int e = 0; e < 8; e++) act[e] += fabsf(rf[e]);
        ABFrag a = pack8(rf);
        #pragma unroll
        for (int nt = 0; nt < 2; nt++) {
            f32x4 am = { bmc[nt], bmc[nt], bmc[nt], bmc[nt] };
            am = MFMA(a.v, WmB[nt].v, am);
            #pragma unroll
            for (int r = 0; r < 4; r++) aggC[nt][r] += fgelu(am[r]);
        }
    }

    // ---- agg/14 -> A-frag (transpose bounce)
    ABFrag aggA;
    BOUNCE(aggA, aggC, (1.0f / 14.0f));

    // ---- h = x + tanh([x,agg]@Wu + bu); yf = h + DT*tanh(h@Wc + bc)
    float hC[2][4], yfC[2][4];
    #pragma unroll
    for (int nt = 0; nt < 2; nt++) {
        f32x4 acc = { buc[nt], buc[nt], buc[nt], buc[nt] };
        acc = MFMA(xA.v,   WuB[0][nt].v, acc);
        acc = MFMA(aggA.v, WuB[1][nt].v, acc);
        #pragma unroll
        for (int r = 0; r < 4; r++) hC[nt][r] = xC[nt][r] + ftanh(acc[r]);
    }
    ABFrag hA;
    BOUNCE(hA, hC, 1.0f);
    #pragma unroll
    for (int nt = 0; nt < 2; nt++) {
        f32x4 acc = { bcc[nt], bcc[nt], bcc[nt], bcc[nt] };
        acc = MFMA(hA.v, WcB[nt].v, acc);
        #pragma unroll
        for (int r = 0; r < 4; r++) yfC[nt][r] = hC[nt][r] + DTC * ftanh(acc[r]);
    }

    // ---- dist rows 17..25 -> fp32 avg ; act accum
    float distf[8];
    #pragma unroll
    for (int e = 0; e < 8; e++) distf[e] = 0.0f;
    #pragma unroll 3
    for (int k = 0; k < 9; k++) {
        float rf[8];
        load_row8(nb + ((size_t)(b0 + lr) * 26 + 17 + k) * S + 8 * lg, rf);
        #pragma unroll
        for (int e = 0; e < 8; e++) { distf[e] += rf[e]; act[e] += fabsf(rf[e]); }
    }
    #pragma unroll
    for (int e = 0; e < 8; e++) distf[e] *= (1.0f / 9.0f);
    ABFrag distA = pack8(distf);

    // ---- gate (fp32, wave reductions over lg groups; vectorized table loads)
    {
        float s = 0.0f;
        #pragma unroll
        for (int e = 0; e < 8; e++) s += xf[e];
        s += __shfl_xor(s, 16); s += __shfl_xor(s, 32);
        const float mu = s * (1.0f / S);
        float v = 0.0f;
        #pragma unroll
        for (int e = 0; e < 8; e++) { float d = xf[e] - mu; v += d * d; }
        v += __shfl_xor(v, 16); v += __shfl_xor(v, 32);
        const float rstd = rsqrtf(v * (1.0f / S) + 1e-5f);

        float lngv[8], lnbv[8];
        load_row8(lng + 8 * lg, lngv);
        load_row8(lnb + 8 * lg, lnbv);

        float g1v[8];
        #pragma unroll
        for (int u = 0; u < 8; u++) g1v[u] = 0.0f;
        #pragma unroll
        for (int e = 0; e < 8; e++) {
            const int i = 8 * lg + e;
            const float a  = (xf[e] - mu) * rstd * lngv[e] + lnbv[e];
            const float ac = act[e] * (1.0f / 26.0f);
            float w1[8], w2[8];
            load_row8(gW1 + i * 8, w1);          // row i of gW1 (8 floats)
            load_row8(gW1 + (S + i) * 8, w2);    // row S+i
            #pragma unroll
            for (int u = 0; u < 8; u++) g1v[u] += a * w1[u] + ac * w2[u];
        }
        float l0 = gb2[0], l1 = gb2[1], l2 = gb2[2];
        #pragma unroll
        for (int u = 0; u < 8; u++) {
            float gt = g1v[u];
            gt += __shfl_xor(gt, 16); gt += __shfl_xor(gt, 32);
            const float g = fgelu(gt + gb1[u]);
            l0 += g * gW2[u * 3 + 0];
            l1 += g * gW2[u * 3 + 1];
            l2 += g * gW2[u * 3 + 2];
        }
        const float mx = fmaxf(l0, fmaxf(l1, l2));
        const float e0 = __expf(l0 - mx), e1 = __expf(l1 - mx), e2 = __expf(l2 - mx);
        const float rs = frcp(e0 + e1 + e2);
        if (lg == 0) {
            gbuf[wid][lr][0] = e0 * rs;
            gbuf[wid][lr][1] = e1 * rs;
            gbuf[wid][lr][2] = e2 * rs;
        }
        WAVE_LDS_FENCE();   // gbuf[wid] is per-wave; no block barrier needed
    }

    // ---- CNF: 3 steps; xt in C-layout + A-frag (re-bounced per step)
    float xtC[2][4];
    #pragma unroll
    for (int nt = 0; nt < 2; nt++)
        #pragma unroll
        for (int r = 0; r < 4; r++) xtC[nt][r] = xC[nt][r];
    ABFrag xtA = xA;
    #pragma unroll 1
    for (int it = 0; it < 3; it++) {
        #pragma unroll
        for (int nt = 0; nt < 2; nt++) {
            f32x4 acc = { bdc[nt], bdc[nt], bdc[nt], bdc[nt] };
            acc = MFMA(xtA.v,  WdB[0][nt].v, acc);
            acc = MFMA(distA.v, WdB[1][nt].v, acc);
            #pragma unroll
            for (int r = 0; r < 4; r++) xtC[nt][r] += DTC * ftanh(acc[r]);
        }
        if (it < 2) { BOUNCE(xtA, xtC, 1.0f); }
    }

    // ---- combine + store (C-layout rows coalesced)
    #pragma unroll
    for (int nt = 0; nt < 2; nt++)
        #pragma unroll
        for (int r = 0; r < 4; r++) {
            const int brow = 4 * lg + r;
            const float g0 = gbuf[wid][brow][0];
            const float g1 = gbuf[wid][brow][1];
            const float g2 = gbuf[wid][brow][2];
            out[(size_t)(b0 + brow) * S + lr + 16 * nt] =
                g0 * ylC[nt][r] + g1 * yfC[nt][r] + g2 * xtC[nt][r];
        }
    if (lg == 0) {
        float* gp = out + (size_t)B * S + (size_t)(b0 + lr) * 3;
        gp[0] = gbuf[wid][lr][0];
        gp[1] = gbuf[wid][lr][1];
        gp[2] = gbuf[wid][lr][2];
    }
}

extern "C" void kernel_launch(void* const* d_in, const int* in_sizes, int n_in,
                              void* d_out, int out_size, void* d_ws, size_t ws_size,
                              hipStream_t stream)
{
    const int B = in_sizes[0] / S;
    dim3 block(256);
    dim3 grid((B + 63) / 64);   // 64 batch per block (4 waves x 16)
    hipLaunchKernelGGL(moe_kernel, grid, block, 0, stream,
        (const float*)d_in[0],  (const float*)d_in[1],
        (const float*)d_in[2],  (const float*)d_in[3],
        (const float*)d_in[4],  (const float*)d_in[5],
        (const float*)d_in[6],  (const float*)d_in[7],
        (const float*)d_in[8],  (const float*)d_in[9],
        (const float*)d_in[10], (const float*)d_in[11],
        (const float*)d_in[12], (const float*)d_in[13],
        (const float*)d_in[14], (const float*)d_in[15],
        (const float*)d_in[16], (const float*)d_in[17],
        (float*)d_out, B);
}